// Round 8
// baseline (297.305 us; speedup 1.0000x reference)
//
#include <hip/hip_runtime.h>
#include <hip/hip_bf16.h>

#define N_NODES 50000
#define N_EDGES 600000
#define NMETA   3
#define LTOT (NMETA * N_NODES)          // 150000
#define SPAN_SHIFT 9
#define NBUCK 98                         // ceil(50000 / 512)
#define BCAP 8192
#define LOG2E 1.4426950408889634f

typedef unsigned short u16;
typedef short bf16x8 __attribute__((ext_vector_type(8)));
typedef float f32x4 __attribute__((ext_vector_type(4)));

__device__ __forceinline__ float bf2f(u16 v) {
    union { unsigned int u; float f; } x; x.u = ((unsigned int)v) << 16; return x.f;
}
__device__ __forceinline__ u16 f2bf(float f) {
    return __hip_bfloat16_raw(__float2bfloat16(f)).x;
}

// ---------------- P2: W,W1 f32 -> bf16 transposed ----------------
__global__ __launch_bounds__(256) void k_prep_w(
    const float* __restrict__ W, const float* __restrict__ W1,
    u16* __restrict__ WT, u16* __restrict__ W1T)
{
    int idx = blockIdx.x * 256 + threadIdx.x;     // 65536 total
    if (idx < NMETA * 16384) {
        int m = idx >> 14, r = idx & 16383;
        int col = r >> 7, k = r & 127;
        WT[idx] = f2bf(W[(m << 14) + k * 128 + col]);
    } else {
        int r = idx - NMETA * 16384;
        int col = r >> 7, k = r & 127;
        W1T[r] = f2bf(W1[k * 128 + col]);
    }
}

// ---------------- K1: h[m] = x @ W[m] (all m), fused alphas (pre-scaled by LOG2E) ----------------
__global__ __launch_bounds__(256) void k_gemm_h(
    const float* __restrict__ x,        // [N,128] f32
    const u16* __restrict__ WT,         // [M,128(col),128(k)] bf16
    const float* __restrict__ att_src,  // [M,128] f32
    const float* __restrict__ att_dst,
    u16* __restrict__ h,                // [M,N,128] bf16
    float* __restrict__ alpha_s,        // [M,N,4]  (×LOG2E)
    float* __restrict__ alpha_d)
{
    const int wv = threadIdx.x >> 6, lane = threadIdx.x & 63;
    const int row0 = (blockIdx.x * 4 + wv) * 16;
    if (row0 >= N_NODES) return;
    const int lhi = lane >> 4, llo = lane & 15;
    // A fragments: load f32, convert once, reuse for all 3 metapaths
    const float* xrow = x + (size_t)(row0 + llo) * 128 + lhi * 8;
    bf16x8 a[4];
    #pragma unroll
    for (int ks = 0; ks < 4; ++ks) {
        float4 f0 = *(const float4*)(xrow + ks * 32);
        float4 f1 = *(const float4*)(xrow + ks * 32 + 4);
        bf16x8 av;
        av[0] = f2bf(f0.x); av[1] = f2bf(f0.y); av[2] = f2bf(f0.z); av[3] = f2bf(f0.w);
        av[4] = f2bf(f1.x); av[5] = f2bf(f1.y); av[6] = f2bf(f1.z); av[7] = f2bf(f1.w);
        a[ks] = av;
    }
    for (int m = 0; m < NMETA; ++m) {
        const u16* wbase = WT + (size_t)m * 16384 + (size_t)llo * 128 + lhi * 8;
        u16* hm = h + ((size_t)m * N_NODES + row0) * 128;
        float sp[4][4], dp[4][4];           // [hh][r]
        #pragma unroll
        for (int i = 0; i < 4; ++i)
            #pragma unroll
            for (int r = 0; r < 4; ++r) { sp[i][r] = 0.f; dp[i][r] = 0.f; }
        #pragma unroll
        for (int cf = 0; cf < 8; ++cf) {
            f32x4 acc = {0.f, 0.f, 0.f, 0.f};
            const u16* wp = wbase + cf * 16 * 128;
            #pragma unroll
            for (int ks = 0; ks < 4; ++ks) {
                bf16x8 b = *(const bf16x8*)(wp + ks * 32);
                acc = __builtin_amdgcn_mfma_f32_16x16x32_bf16(a[ks], b, acc, 0, 0, 0);
            }
            const int col = cf * 16 + llo;
            const int hh = cf >> 1;
            const float as = att_src[m * 128 + col];
            const float adv = att_dst[m * 128 + col];
            #pragma unroll
            for (int r = 0; r < 4; ++r) {
                hm[(size_t)(lhi * 4 + r) * 128 + col] = f2bf(acc[r]);
                sp[hh][r] += acc[r] * as;
                dp[hh][r] += acc[r] * adv;
            }
        }
        #pragma unroll
        for (int o = 1; o <= 8; o <<= 1) {
            #pragma unroll
            for (int i = 0; i < 4; ++i)
                #pragma unroll
                for (int r = 0; r < 4; ++r) {
                    sp[i][r] += __shfl_xor(sp[i][r], o);
                    dp[i][r] += __shfl_xor(dp[i][r], o);
                }
        }
        if (llo == 0) {
            #pragma unroll
            for (int r = 0; r < 4; ++r) {
                int n = row0 + lhi * 4 + r;
                f32x4 vs = {sp[0][r] * LOG2E, sp[1][r] * LOG2E, sp[2][r] * LOG2E, sp[3][r] * LOG2E};
                f32x4 vd = {dp[0][r] * LOG2E, dp[1][r] * LOG2E, dp[2][r] * LOG2E, dp[3][r] * LOG2E};
                *(f32x4*)(alpha_s + ((size_t)m * N_NODES + n) * 4) = vs;
                *(f32x4*)(alpha_d + ((size_t)m * N_NODES + n) * 4) = vd;
            }
        }
    }
}

// ---------------- CSR A: bin edges into bucket regions ----------------
__global__ __launch_bounds__(256) void k_csrA(
    const int* __restrict__ ei, int* __restrict__ gcnt,
    unsigned long long* __restrict__ pairs)
{
    const int m = blockIdx.y;
    __shared__ int cnt[NBUCK];
    __shared__ int gbase[NBUCK];
    const int t = threadIdx.x;
    if (t < NBUCK) cnt[t] = 0;
    __syncthreads();
    const int e0 = blockIdx.x * 4096;
    const int* srcp = ei + (size_t)m * 2 * N_EDGES;
    const int* dstp = srcp + N_EDGES;
    int sa[16], da[16], sl[16];
    #pragma unroll
    for (int j = 0; j < 16; ++j) {
        int e = e0 + j * 256 + t;
        if (e < N_EDGES) {
            int s = srcp[e], d = dstp[e];
            if ((unsigned)s >= N_NODES) s = 0;
            if ((unsigned)d >= N_NODES) d = 0;
            sa[j] = s; da[j] = d;
            sl[j] = atomicAdd(&cnt[d >> SPAN_SHIFT], 1);
        } else sl[j] = -1;
    }
    __syncthreads();
    if (t < NBUCK) gbase[t] = atomicAdd(&gcnt[m * NBUCK + t], cnt[t]);
    __syncthreads();
    #pragma unroll
    for (int j = 0; j < 16; ++j) {
        if (sl[j] < 0) continue;
        int b = da[j] >> SPAN_SHIFT;
        int pos = gbase[b] + sl[j];
        if (pos < BCAP)
            pairs[(size_t)(m * NBUCK + b) * BCAP + pos] =
                ((unsigned long long)(da[j] & 511) << 32) | (unsigned)(sa[j] * 128);
    }
}

// ---------------- CSR B: per-bucket count+scan+place ----------------
__global__ __launch_bounds__(256) void k_csrB(
    const int* __restrict__ gcnt, const unsigned long long* __restrict__ pairs,
    int* __restrict__ row_start, int* __restrict__ row_end, int* __restrict__ eidx)
{
    const int m = blockIdx.y, b = blockIdx.x;
    const int t = threadIdx.x;
    __shared__ int cnt[512];
    __shared__ int off[512];
    __shared__ int wsum[4];
    int nb = gcnt[m * NBUCK + b]; if (nb > BCAP) nb = BCAP;
    const int base = (m * NBUCK + b) * BCAP;
    cnt[t] = 0; cnt[t + 256] = 0;
    __syncthreads();
    for (int e = t; e < nb; e += 256) {
        int dl = (int)(pairs[(size_t)base + e] >> 32);
        atomicAdd(&cnt[dl], 1);
    }
    __syncthreads();
    int v0 = cnt[2 * t], v1 = cnt[2 * t + 1];
    int s = v0 + v1;
    int lane = t & 63, wv = t >> 6;
    int incl = s;
    #pragma unroll
    for (int o = 1; o < 64; o <<= 1) {
        int u = __shfl_up(incl, o);
        if (lane >= o) incl += u;
    }
    if (lane == 63) wsum[wv] = incl;
    __syncthreads();
    int woff = 0;
    for (int i = 0; i < wv; ++i) woff += wsum[i];
    int ex = woff + incl - s;
    off[2 * t] = ex;
    off[2 * t + 1] = ex + v0;
    __syncthreads();
    const int node0 = b << SPAN_SHIFT;
    for (int i = t; i < 512; i += 256) {
        int n = node0 + i;
        if (n < N_NODES) {
            int st = base + off[i];
            row_start[m * N_NODES + n] = st;
            row_end[m * N_NODES + n]   = st + cnt[i];
        }
    }
    __syncthreads();
    for (int e = t; e < nb; e += 256) {
        unsigned long long p = pairs[(size_t)base + e];
        int dl = (int)(p >> 32);
        int pos = atomicAdd(&off[dl], 1);
        eidx[(size_t)base + pos] = (int)(unsigned)p;   // src*128
    }
}

// ---------------- K2: gather, lane-parallel alpha chain (16 edges/pass) ----------------
__global__ __launch_bounds__(256) void k_gather(
    const int* __restrict__ row_start, const int* __restrict__ row_end,
    const int* __restrict__ eidx,
    const float* __restrict__ alpha_s, const float* __restrict__ alpha_d,
    const u16* __restrict__ h,
    const float* __restrict__ bias, const float* __restrict__ gamma,
    const float* __restrict__ lbeta,
    u16* __restrict__ z)                 // [N, M, 128] bf16
{
    long long w = ((long long)blockIdx.x * blockDim.x + threadIdx.x) >> 6;
    if (w >= (long long)LTOT) return;
    int m = (int)(w / N_NODES), n = (int)(w % N_NODES);
    int lane = threadIdx.x & 63;
    int hh = lane >> 4;                  // accumulation/epilogue head (cols lane*2..+1)
    int hc = lane & 3;                   // chain-phase head
    const float* as_m = alpha_s + (size_t)m * N_NODES * 4;
    const float* ad_m = alpha_d + (size_t)m * N_NODES * 4;
    const u16*   h_m  = h + (size_t)m * N_NODES * 128;
    // self loop (per-lane, head hh)
    float pre_s = as_m[n * 4 + hh] + ad_m[n * 4 + hh];
    pre_s = fmaxf(pre_s, 0.2f * pre_s);
    float e_self = exp2f(pre_s);
    ushort2 hv = *(const ushort2*)(h_m + n * 128 + lane * 2);
    float acc0 = e_self * bf2f(hv.x), acc1 = e_self * bf2f(hv.y);
    // chain-phase per-lane dst alpha (head hc)
    float ad_hc = ad_m[n * 4 + hc];
    const int start = row_start[m * N_NODES + n];
    const int end   = row_end[m * N_NODES + n];
    float esum_l = 0.f;
    for (int p = start; p < end; p += 16) {
        int ep = p + (lane >> 2);
        int off = 0;
        float e = 0.f;
        if (ep < end) {
            off = eidx[ep];                       // src*128
            float pre = as_m[(off >> 5) + hc] + ad_hc;
            pre = fmaxf(pre, 0.2f * pre);
            e = exp2f(pre);
        }
        esum_l += e;
        #pragma unroll
        for (int j = 0; j < 16; ++j) {
            float eb = __shfl(e, j * 4 + hh);
            int   ob = __shfl(off, j * 4);
            ushort2 hj = *(const ushort2*)(h_m + ob + lane * 2);
            acc0 += eb * bf2f(hj.x);
            acc1 += eb * bf2f(hj.y);
        }
    }
    // reduce esum over the 16 slots (lanes sharing lane&3)
    esum_l += __shfl_xor(esum_l, 4);
    esum_l += __shfl_xor(esum_l, 8);
    esum_l += __shfl_xor(esum_l, 16);
    esum_l += __shfl_xor(esum_l, 32);
    float esum = __shfl(esum_l, hh) + e_self;     // lane 'hh' holds head-hh sum
    float rinv = 1.f / (esum + 1e-16f);
    float v0 = acc0 * rinv + bias[m * 128 + lane * 2];
    float v1 = acc1 * rinv + bias[m * 128 + lane * 2 + 1];
    float s1 = v0 + v1, s2 = v0 * v0 + v1 * v1;
    #pragma unroll
    for (int o = 32; o >= 1; o >>= 1) { s1 += __shfl_xor(s1, o); s2 += __shfl_xor(s2, o); }
    float mu = s1 * (1.f / 128.f);
    float var = s2 * (1.f / 128.f) - mu * mu;
    float rs = rsqrtf(var + 1e-5f);
    float o0 = (v0 - mu) * rs * gamma[lane * 2]     + lbeta[lane * 2];
    float o1 = (v1 - mu) * rs * gamma[lane * 2 + 1] + lbeta[lane * 2 + 1];
    o0 = o0 > 0.f ? o0 : (__expf(o0) - 1.f);
    o1 = o1 > 0.f ? o1 : (__expf(o1) - 1.f);
    ushort2 outv; outv.x = f2bf(o0); outv.y = f2bf(o1);
    *(ushort2*)(z + ((size_t)n * NMETA + m) * 128 + lane * 2) = outv;
}

// ---------------- K4: semantic scores via MFMA ----------------
__global__ __launch_bounds__(256) void k_sem(
    const u16* __restrict__ z,     // [LTOT,128] bf16 (row = n*3+m)
    const u16* __restrict__ W1T,   // [128(col),128(k)] bf16
    const float* __restrict__ b1,  // [128]
    const float* __restrict__ W2,  // [128]
    float* __restrict__ wpart)     // [M]
{
    __shared__ float part[NMETA];
    const int t = threadIdx.x;
    if (t < NMETA) part[t] = 0.f;
    __syncthreads();
    const int wv = t >> 6, lane = t & 63;
    const int row0 = (blockIdx.x * 4 + wv) * 16;
    if (row0 < LTOT) {
        const int lhi = lane >> 4, llo = lane & 15;
        const u16* zrow = z + (size_t)(row0 + llo) * 128 + lhi * 8;
        bf16x8 a[4];
        #pragma unroll
        for (int ks = 0; ks < 4; ++ks) a[ks] = *(const bf16x8*)(zrow + ks * 32);
        const u16* wb = W1T + (size_t)llo * 128 + lhi * 8;
        float rowacc[4] = {0.f, 0.f, 0.f, 0.f};
        #pragma unroll
        for (int cf = 0; cf < 8; ++cf) {
            f32x4 acc = {0.f, 0.f, 0.f, 0.f};
            const u16* wp = wb + cf * 16 * 128;
            #pragma unroll
            for (int ks = 0; ks < 4; ++ks) {
                bf16x8 bb = *(const bf16x8*)(wp + ks * 32);
                acc = __builtin_amdgcn_mfma_f32_16x16x32_bf16(a[ks], bb, acc, 0, 0, 0);
            }
            int col = cf * 16 + llo;
            float b1v = b1[col], w2v = W2[col];
            #pragma unroll
            for (int r = 0; r < 4; ++r)
                rowacc[r] += tanhf(acc[r] + b1v) * w2v;
        }
        #pragma unroll
        for (int o = 1; o <= 8; o <<= 1) {
            #pragma unroll
            for (int r = 0; r < 4; ++r) rowacc[r] += __shfl_xor(rowacc[r], o);
        }
        if (llo == 0) {
            #pragma unroll
            for (int r = 0; r < 4; ++r)
                atomicAdd(&part[(row0 + lhi * 4 + r) % NMETA], rowacc[r]);
        }
    }
    __syncthreads();
    if (t < NMETA) atomicAdd(&wpart[t], part[t]);
}

// ---------------- K5: beta = softmax(wpart / N); write att_mp ----------------
__global__ void k_beta(const float* __restrict__ wpart, float* __restrict__ betab,
                       float* __restrict__ attout)
{
    if (threadIdx.x == 0 && blockIdx.x == 0) {
        float w0 = wpart[0] * (1.f / N_NODES);
        float w1 = wpart[1] * (1.f / N_NODES);
        float w2 = wpart[2] * (1.f / N_NODES);
        float mx = fmaxf(w0, fmaxf(w1, w2));
        float e0 = __expf(w0 - mx), e1 = __expf(w1 - mx), e2 = __expf(w2 - mx);
        float s = 1.f / (e0 + e1 + e2);
        float b0 = e0 * s, b1 = e1 * s, b2 = e2 * s;
        betab[0] = b0; betab[1] = b1; betab[2] = b2;
        attout[0] = b0; attout[1] = b1; attout[2] = b2;
    }
}

// ---------------- K6: out_emb = sum_m beta[m] * z[:,m,:] ----------------
__global__ __launch_bounds__(256) void k_combine(
    const u16* __restrict__ z, const float* __restrict__ betab,
    float* __restrict__ out)
{
    int idx = blockIdx.x * blockDim.x + threadIdx.x;
    if (idx >= N_NODES * 64) return;
    int n = idx >> 6, c2 = (idx & 63) * 2;
    float b0 = betab[0], b1 = betab[1], b2 = betab[2];
    const u16* zp = z + (size_t)n * NMETA * 128 + c2;
    ushort2 a0 = *(const ushort2*)(zp);
    ushort2 a1 = *(const ushort2*)(zp + 128);
    ushort2 a2 = *(const ushort2*)(zp + 256);
    float2 ov;
    ov.x = b0 * bf2f(a0.x) + b1 * bf2f(a1.x) + b2 * bf2f(a2.x);
    ov.y = b0 * bf2f(a0.y) + b1 * bf2f(a1.y) + b2 * bf2f(a2.y);
    *(float2*)(out + (size_t)n * 128 + c2) = ov;
}

extern "C" void kernel_launch(void* const* d_in, const int* in_sizes, int n_in,
                              void* d_out, int out_size, void* d_ws, size_t ws_size,
                              hipStream_t stream) {
    const float* x       = (const float*)d_in[0];
    const int*   ei      = (const int*)d_in[1];
    const float* W       = (const float*)d_in[2];
    const float* att_src = (const float*)d_in[3];
    const float* att_dst = (const float*)d_in[4];
    const float* bias    = (const float*)d_in[5];
    const float* gamma   = (const float*)d_in[6];
    const float* lbeta   = (const float*)d_in[7];
    const float* W1      = (const float*)d_in[8];
    const float* b1      = (const float*)d_in[9];
    const float* W2      = (const float*)d_in[10];

    char* ws = (char*)d_ws;
    size_t off = 0;
    int* gcnt    = (int*)(ws + off);  off += sizeof(int) * 512;          // 294 used
    float* wpart = (float*)(ws + off);
    float* betab = wpart + 8;         off += 64;
    const size_t zero_bytes = off;
    off = (off + 255) & ~(size_t)255;
    int* row_start = (int*)(ws + off); off += sizeof(int) * 150016;
    int* row_end   = (int*)(ws + off); off += sizeof(int) * 150016;
    u16* h      = (u16*)(ws + off);    off += sizeof(u16) * (size_t)NMETA * N_NODES * 128;
    float* alpha_s = (float*)(ws + off); off += sizeof(float) * (size_t)LTOT * 4;
    float* alpha_d = (float*)(ws + off); off += sizeof(float) * (size_t)LTOT * 4;
    u16* WT     = (u16*)(ws + off);    off += sizeof(u16) * (size_t)NMETA * 128 * 128;
    u16* W1T    = (u16*)(ws + off);    off += sizeof(u16) * (size_t)128 * 128;
    int* eidx   = (int*)(ws + off);    off += sizeof(int) * (size_t)NMETA * NBUCK * BCAP;
    // union region (disjoint lifetimes): pairs (csrA->csrB), z (gather->end)
    unsigned long long* pairs = (unsigned long long*)(ws + off);
    u16* z = (u16*)(ws + off);
    off += sizeof(u16) * (size_t)N_NODES * NMETA * 128;                  // 38.4 MB (largest)
    if (ws_size < off) return;  // ~93 MB needed; loud failure if undersized

    hipMemsetAsync(d_ws, 0, zero_bytes, stream);

    k_prep_w<<<dim3(256), 256, 0, stream>>>(W, W1, WT, W1T);
    k_gemm_h<<<dim3((N_NODES / 16 + 3) / 4), 256, 0, stream>>>(
        x, WT, att_src, att_dst, h, alpha_s, alpha_d);
    k_csrA<<<dim3((N_EDGES + 4095) / 4096, NMETA), 256, 0, stream>>>(ei, gcnt, pairs);
    k_csrB<<<dim3(NBUCK, NMETA), 256, 0, stream>>>(gcnt, pairs, row_start, row_end, eidx);
    k_gather<<<dim3((LTOT + 3) / 4), 256, 0, stream>>>(row_start, row_end, eidx,
                                                       alpha_s, alpha_d, h,
                                                       bias, gamma, lbeta, z);
    k_sem<<<dim3((LTOT / 16 + 3) / 4), 256, 0, stream>>>(z, W1T, b1, W2, wpart);
    k_beta<<<1, 64, 0, stream>>>(wpart, betab, (float*)d_out + (size_t)N_NODES * 128);
    k_combine<<<dim3((N_NODES * 64 + 255) / 256), 256, 0, stream>>>(z, betab, (float*)d_out);
}

// Round 9
// 274.174 us; speedup vs baseline: 1.0844x; 1.0844x over previous
//
#include <hip/hip_runtime.h>
#include <hip/hip_bf16.h>

#define N_NODES 50000
#define N_EDGES 600000
#define NMETA   3
#define LTOT (NMETA * N_NODES)          // 150000
#define SPAN_SHIFT 9
#define NBUCK 98                         // ceil(50000 / 512)
#define BCAP 8192
#define NCHUNK 147                       // ceil(600000 / 4096)
#define LOG2E 1.4426950408889634f

typedef unsigned short u16;
typedef short bf16x8 __attribute__((ext_vector_type(8)));
typedef float f32x4 __attribute__((ext_vector_type(4)));

__device__ __forceinline__ float bf2f(u16 v) {
    union { unsigned int u; float f; } x; x.u = ((unsigned int)v) << 16; return x.f;
}
__device__ __forceinline__ u16 f2bf(float f) {
    return __hip_bfloat16_raw(__float2bfloat16(f)).x;
}

// ---------------- build1: csrA (blocks 0..440)  ||  prep_w (blocks 441..696) ----------------
__global__ __launch_bounds__(256) void k_build1(
    const int* __restrict__ ei, int* __restrict__ gcnt,
    unsigned long long* __restrict__ pairs,
    const float* __restrict__ W, const float* __restrict__ W1,
    u16* __restrict__ WT, u16* __restrict__ W1T)
{
    const int bid = blockIdx.x;
    const int t = threadIdx.x;
    if (bid >= NMETA * NCHUNK) {
        // ---- prep_w ----
        int idx = (bid - NMETA * NCHUNK) * 256 + t;
        if (idx < NMETA * 16384) {
            int m = idx >> 14, r = idx & 16383;
            int col = r >> 7, k = r & 127;
            WT[idx] = f2bf(W[(m << 14) + k * 128 + col]);
        } else {
            int r = idx - NMETA * 16384;
            int col = r >> 7, k = r & 127;
            W1T[r] = f2bf(W1[k * 128 + col]);
        }
        return;
    }
    // ---- csrA ----
    const int m = bid / NCHUNK;
    const int e0 = (bid % NCHUNK) * 4096;
    __shared__ int cnt[NBUCK];
    __shared__ int gbase[NBUCK];
    if (t < NBUCK) cnt[t] = 0;
    __syncthreads();
    const int* srcp = ei + (size_t)m * 2 * N_EDGES;
    const int* dstp = srcp + N_EDGES;
    int sa[16], da[16], sl[16];
    #pragma unroll
    for (int j = 0; j < 16; ++j) {
        int e = e0 + j * 256 + t;
        if (e < N_EDGES) {
            int s = srcp[e], d = dstp[e];
            if ((unsigned)s >= N_NODES) s = 0;
            if ((unsigned)d >= N_NODES) d = 0;
            sa[j] = s; da[j] = d;
            sl[j] = atomicAdd(&cnt[d >> SPAN_SHIFT], 1);
        } else sl[j] = -1;
    }
    __syncthreads();
    if (t < NBUCK) gbase[t] = atomicAdd(&gcnt[m * NBUCK + t], cnt[t]);
    __syncthreads();
    #pragma unroll
    for (int j = 0; j < 16; ++j) {
        if (sl[j] < 0) continue;
        int b = da[j] >> SPAN_SHIFT;
        int pos = gbase[b] + sl[j];
        if (pos < BCAP)
            pairs[(size_t)(m * NBUCK + b) * BCAP + pos] =
                ((unsigned long long)(da[j] & 511) << 32) | (unsigned)(sa[j] * 128);
    }
}

// ---------------- build2: csrB (blocks 0..293)  ||  gemm_h+alpha (blocks 294..2639) ----------------
__global__ __launch_bounds__(256) void k_build2(
    const int* __restrict__ gcnt, const unsigned long long* __restrict__ pairs,
    int* __restrict__ row_start, int* __restrict__ row_end, int* __restrict__ eidx,
    const float* __restrict__ x, const u16* __restrict__ WT,
    const float* __restrict__ att_src, const float* __restrict__ att_dst,
    u16* __restrict__ h, float* __restrict__ alpha_s, float* __restrict__ alpha_d)
{
    const int bid = blockIdx.x;
    const int t = threadIdx.x;
    if (bid < NMETA * NBUCK) {
        // ---- csrB ----
        const int m = bid / NBUCK, b = bid % NBUCK;
        __shared__ int cnt[512];
        __shared__ int off[512];
        __shared__ int wsum[4];
        int nb = gcnt[m * NBUCK + b]; if (nb > BCAP) nb = BCAP;
        const int base = (m * NBUCK + b) * BCAP;
        cnt[t] = 0; cnt[t + 256] = 0;
        __syncthreads();
        for (int e = t; e < nb; e += 256) {
            int dl = (int)(pairs[(size_t)base + e] >> 32);
            atomicAdd(&cnt[dl], 1);
        }
        __syncthreads();
        int v0 = cnt[2 * t], v1 = cnt[2 * t + 1];
        int s = v0 + v1;
        int lane = t & 63, wv = t >> 6;
        int incl = s;
        #pragma unroll
        for (int o = 1; o < 64; o <<= 1) {
            int u = __shfl_up(incl, o);
            if (lane >= o) incl += u;
        }
        if (lane == 63) wsum[wv] = incl;
        __syncthreads();
        int woff = 0;
        for (int i = 0; i < wv; ++i) woff += wsum[i];
        int ex = woff + incl - s;
        off[2 * t] = ex;
        off[2 * t + 1] = ex + v0;
        __syncthreads();
        const int node0 = b << SPAN_SHIFT;
        for (int i = t; i < 512; i += 256) {
            int n = node0 + i;
            if (n < N_NODES) {
                int st = base + off[i];
                row_start[m * N_NODES + n] = st;
                row_end[m * N_NODES + n]   = st + cnt[i];
            }
        }
        __syncthreads();
        for (int e = t; e < nb; e += 256) {
            unsigned long long p = pairs[(size_t)base + e];
            int dl = (int)(p >> 32);
            int pos = atomicAdd(&off[dl], 1);
            eidx[(size_t)base + pos] = (int)(unsigned)p;   // src*128
        }
        return;
    }
    // ---- gemm_h + fused alphas (pre-scaled by LOG2E) ----
    const int g = bid - NMETA * NBUCK;
    const int bx = g % 782, m = g / 782;
    const int wv = t >> 6, lane = t & 63;
    const int row0 = (bx * 4 + wv) * 16;
    if (row0 >= N_NODES) return;
    const int lhi = lane >> 4, llo = lane & 15;
    const float* xrow = x + (size_t)(row0 + llo) * 128 + lhi * 8;
    bf16x8 a[4];
    #pragma unroll
    for (int ks = 0; ks < 4; ++ks) {
        float4 f0 = *(const float4*)(xrow + ks * 32);
        float4 f1 = *(const float4*)(xrow + ks * 32 + 4);
        bf16x8 av;
        av[0] = f2bf(f0.x); av[1] = f2bf(f0.y); av[2] = f2bf(f0.z); av[3] = f2bf(f0.w);
        av[4] = f2bf(f1.x); av[5] = f2bf(f1.y); av[6] = f2bf(f1.z); av[7] = f2bf(f1.w);
        a[ks] = av;
    }
    const u16* wbase = WT + (size_t)m * 16384 + (size_t)llo * 128 + lhi * 8;
    u16* hm = h + ((size_t)m * N_NODES + row0) * 128;
    float sp[4][4], dp[4][4];           // [hh][r]
    #pragma unroll
    for (int i = 0; i < 4; ++i)
        #pragma unroll
        for (int r = 0; r < 4; ++r) { sp[i][r] = 0.f; dp[i][r] = 0.f; }
    #pragma unroll
    for (int cf = 0; cf < 8; ++cf) {
        f32x4 acc = {0.f, 0.f, 0.f, 0.f};
        const u16* wp = wbase + cf * 16 * 128;
        #pragma unroll
        for (int ks = 0; ks < 4; ++ks) {
            bf16x8 b = *(const bf16x8*)(wp + ks * 32);
            acc = __builtin_amdgcn_mfma_f32_16x16x32_bf16(a[ks], b, acc, 0, 0, 0);
        }
        const int col = cf * 16 + llo;
        const int hh = cf >> 1;
        const float as = att_src[m * 128 + col];
        const float adv = att_dst[m * 128 + col];
        #pragma unroll
        for (int r = 0; r < 4; ++r) {
            hm[(size_t)(lhi * 4 + r) * 128 + col] = f2bf(acc[r]);
            sp[hh][r] += acc[r] * as;
            dp[hh][r] += acc[r] * adv;
        }
    }
    #pragma unroll
    for (int o = 1; o <= 8; o <<= 1) {
        #pragma unroll
        for (int i = 0; i < 4; ++i)
            #pragma unroll
            for (int r = 0; r < 4; ++r) {
                sp[i][r] += __shfl_xor(sp[i][r], o);
                dp[i][r] += __shfl_xor(dp[i][r], o);
            }
    }
    if (llo == 0) {
        #pragma unroll
        for (int r = 0; r < 4; ++r) {
            int n = row0 + lhi * 4 + r;
            f32x4 vs = {sp[0][r] * LOG2E, sp[1][r] * LOG2E, sp[2][r] * LOG2E, sp[3][r] * LOG2E};
            f32x4 vd = {dp[0][r] * LOG2E, dp[1][r] * LOG2E, dp[2][r] * LOG2E, dp[3][r] * LOG2E};
            *(f32x4*)(alpha_s + ((size_t)m * N_NODES + n) * 4) = vs;
            *(f32x4*)(alpha_d + ((size_t)m * N_NODES + n) * 4) = vd;
        }
    }
}

// ---------------- K2: gather + softmax + bias + LN + ELU (R7 form, exp2) ----------------
__global__ __launch_bounds__(256) void k_gather(
    const int* __restrict__ row_start, const int* __restrict__ row_end,
    const int* __restrict__ eidx,
    const float* __restrict__ alpha_s, const float* __restrict__ alpha_d,
    const u16* __restrict__ h,
    const float* __restrict__ bias, const float* __restrict__ gamma,
    const float* __restrict__ lbeta,
    u16* __restrict__ z)                 // [N, M, 128] bf16
{
    long long w = ((long long)blockIdx.x * blockDim.x + threadIdx.x) >> 6;
    if (w >= (long long)LTOT) return;
    int m = (int)(w / N_NODES), n = (int)(w % N_NODES);
    int lane = threadIdx.x & 63, hh = lane >> 4;
    const float* as_m = alpha_s + (size_t)m * N_NODES * 4;
    const float* ad_m = alpha_d + (size_t)m * N_NODES * 4;
    const u16*   h_m  = h + (size_t)m * N_NODES * 128;
    float ad = ad_m[n * 4 + hh];
    // self loop
    float pre = as_m[n * 4 + hh] + ad;
    pre = fmaxf(pre, 0.2f * pre);
    float ev = exp2f(pre);
    float esum = ev;
    ushort2 hv = *(const ushort2*)(h_m + n * 128 + lane * 2);
    float acc0 = ev * bf2f(hv.x), acc1 = ev * bf2f(hv.y);
    int p = row_start[m * N_NODES + n];
    const int end = row_end[m * N_NODES + n];
    for (; p + 3 < end; p += 4) {
        int o1 = eidx[p], o2 = eidx[p + 1], o3 = eidx[p + 2], o4 = eidx[p + 3];
        float p1 = as_m[(o1 >> 5) + hh] + ad;
        float p2 = as_m[(o2 >> 5) + hh] + ad;
        float p3 = as_m[(o3 >> 5) + hh] + ad;
        float p4 = as_m[(o4 >> 5) + hh] + ad;
        ushort2 h1 = *(const ushort2*)(h_m + o1 + lane * 2);
        ushort2 h2 = *(const ushort2*)(h_m + o2 + lane * 2);
        ushort2 h3 = *(const ushort2*)(h_m + o3 + lane * 2);
        ushort2 h4 = *(const ushort2*)(h_m + o4 + lane * 2);
        p1 = fmaxf(p1, 0.2f * p1);
        p2 = fmaxf(p2, 0.2f * p2);
        p3 = fmaxf(p3, 0.2f * p3);
        p4 = fmaxf(p4, 0.2f * p4);
        float e1 = exp2f(p1), e2 = exp2f(p2), e3 = exp2f(p3), e4 = exp2f(p4);
        esum += (e1 + e2) + (e3 + e4);
        acc0 += e1 * bf2f(h1.x) + e2 * bf2f(h2.x) + e3 * bf2f(h3.x) + e4 * bf2f(h4.x);
        acc1 += e1 * bf2f(h1.y) + e2 * bf2f(h2.y) + e3 * bf2f(h3.y) + e4 * bf2f(h4.y);
    }
    for (; p < end; ++p) {
        int o1 = eidx[p];
        float p1 = as_m[(o1 >> 5) + hh] + ad;
        ushort2 h1 = *(const ushort2*)(h_m + o1 + lane * 2);
        p1 = fmaxf(p1, 0.2f * p1);
        float e1 = exp2f(p1);
        esum += e1;
        acc0 += e1 * bf2f(h1.x);
        acc1 += e1 * bf2f(h1.y);
    }
    float rinv = 1.f / (esum + 1e-16f);
    float v0 = acc0 * rinv + bias[m * 128 + lane * 2];
    float v1 = acc1 * rinv + bias[m * 128 + lane * 2 + 1];
    float s1 = v0 + v1, s2 = v0 * v0 + v1 * v1;
    #pragma unroll
    for (int o = 32; o >= 1; o >>= 1) { s1 += __shfl_xor(s1, o); s2 += __shfl_xor(s2, o); }
    float mu = s1 * (1.f / 128.f);
    float var = s2 * (1.f / 128.f) - mu * mu;
    float rs = rsqrtf(var + 1e-5f);
    float o0 = (v0 - mu) * rs * gamma[lane * 2]     + lbeta[lane * 2];
    float o1 = (v1 - mu) * rs * gamma[lane * 2 + 1] + lbeta[lane * 2 + 1];
    o0 = o0 > 0.f ? o0 : (__expf(o0) - 1.f);
    o1 = o1 > 0.f ? o1 : (__expf(o1) - 1.f);
    ushort2 outv; outv.x = f2bf(o0); outv.y = f2bf(o1);
    *(ushort2*)(z + ((size_t)n * NMETA + m) * 128 + lane * 2) = outv;
}

// ---------------- K4: semantic scores via MFMA ----------------
__global__ __launch_bounds__(256) void k_sem(
    const u16* __restrict__ z,     // [LTOT,128] bf16 (row = n*3+m)
    const u16* __restrict__ W1T,   // [128(col),128(k)] bf16
    const float* __restrict__ b1,  // [128]
    const float* __restrict__ W2,  // [128]
    float* __restrict__ wpart)     // [M]
{
    __shared__ float part[NMETA];
    const int t = threadIdx.x;
    if (t < NMETA) part[t] = 0.f;
    __syncthreads();
    const int wv = t >> 6, lane = t & 63;
    const int row0 = (blockIdx.x * 4 + wv) * 16;
    if (row0 < LTOT) {
        const int lhi = lane >> 4, llo = lane & 15;
        const u16* zrow = z + (size_t)(row0 + llo) * 128 + lhi * 8;
        bf16x8 a[4];
        #pragma unroll
        for (int ks = 0; ks < 4; ++ks) a[ks] = *(const bf16x8*)(zrow + ks * 32);
        const u16* wb = W1T + (size_t)llo * 128 + lhi * 8;
        float rowacc[4] = {0.f, 0.f, 0.f, 0.f};
        #pragma unroll
        for (int cf = 0; cf < 8; ++cf) {
            f32x4 acc = {0.f, 0.f, 0.f, 0.f};
            const u16* wp = wb + cf * 16 * 128;
            #pragma unroll
            for (int ks = 0; ks < 4; ++ks) {
                bf16x8 bb = *(const bf16x8*)(wp + ks * 32);
                acc = __builtin_amdgcn_mfma_f32_16x16x32_bf16(a[ks], bb, acc, 0, 0, 0);
            }
            int col = cf * 16 + llo;
            float b1v = b1[col], w2v = W2[col];
            #pragma unroll
            for (int r = 0; r < 4; ++r)
                rowacc[r] += tanhf(acc[r] + b1v) * w2v;
        }
        #pragma unroll
        for (int o = 1; o <= 8; o <<= 1) {
            #pragma unroll
            for (int r = 0; r < 4; ++r) rowacc[r] += __shfl_xor(rowacc[r], o);
        }
        if (llo == 0) {
            #pragma unroll
            for (int r = 0; r < 4; ++r)
                atomicAdd(&part[(row0 + lhi * 4 + r) % NMETA], rowacc[r]);
        }
    }
    __syncthreads();
    if (t < NMETA) atomicAdd(&wpart[t], part[t]);
}

// ---------------- K5: beta = softmax(wpart / N); write att_mp ----------------
__global__ void k_beta(const float* __restrict__ wpart, float* __restrict__ betab,
                       float* __restrict__ attout)
{
    if (threadIdx.x == 0 && blockIdx.x == 0) {
        float w0 = wpart[0] * (1.f / N_NODES);
        float w1 = wpart[1] * (1.f / N_NODES);
        float w2 = wpart[2] * (1.f / N_NODES);
        float mx = fmaxf(w0, fmaxf(w1, w2));
        float e0 = __expf(w0 - mx), e1 = __expf(w1 - mx), e2 = __expf(w2 - mx);
        float s = 1.f / (e0 + e1 + e2);
        float b0 = e0 * s, b1 = e1 * s, b2 = e2 * s;
        betab[0] = b0; betab[1] = b1; betab[2] = b2;
        attout[0] = b0; attout[1] = b1; attout[2] = b2;
    }
}

// ---------------- K6: out_emb = sum_m beta[m] * z[:,m,:] ----------------
__global__ __launch_bounds__(256) void k_combine(
    const u16* __restrict__ z, const float* __restrict__ betab,
    float* __restrict__ out)
{
    int idx = blockIdx.x * blockDim.x + threadIdx.x;
    if (idx >= N_NODES * 64) return;
    int n = idx >> 6, c2 = (idx & 63) * 2;
    float b0 = betab[0], b1 = betab[1], b2 = betab[2];
    const u16* zp = z + (size_t)n * NMETA * 128 + c2;
    ushort2 a0 = *(const ushort2*)(zp);
    ushort2 a1 = *(const ushort2*)(zp + 128);
    ushort2 a2 = *(const ushort2*)(zp + 256);
    float2 ov;
    ov.x = b0 * bf2f(a0.x) + b1 * bf2f(a1.x) + b2 * bf2f(a2.x);
    ov.y = b0 * bf2f(a0.y) + b1 * bf2f(a1.y) + b2 * bf2f(a2.y);
    *(float2*)(out + (size_t)n * 128 + c2) = ov;
}

extern "C" void kernel_launch(void* const* d_in, const int* in_sizes, int n_in,
                              void* d_out, int out_size, void* d_ws, size_t ws_size,
                              hipStream_t stream) {
    const float* x       = (const float*)d_in[0];
    const int*   ei      = (const int*)d_in[1];
    const float* W       = (const float*)d_in[2];
    const float* att_src = (const float*)d_in[3];
    const float* att_dst = (const float*)d_in[4];
    const float* bias    = (const float*)d_in[5];
    const float* gamma   = (const float*)d_in[6];
    const float* lbeta   = (const float*)d_in[7];
    const float* W1      = (const float*)d_in[8];
    const float* b1      = (const float*)d_in[9];
    const float* W2      = (const float*)d_in[10];

    char* ws = (char*)d_ws;
    size_t off = 0;
    int* gcnt    = (int*)(ws + off);  off += sizeof(int) * 512;          // 294 used
    float* wpart = (float*)(ws + off);
    float* betab = wpart + 8;         off += 64;
    const size_t zero_bytes = off;
    off = (off + 255) & ~(size_t)255;
    int* row_start = (int*)(ws + off); off += sizeof(int) * 150016;
    int* row_end   = (int*)(ws + off); off += sizeof(int) * 150016;
    u16* h      = (u16*)(ws + off);    off += sizeof(u16) * (size_t)NMETA * N_NODES * 128;
    float* alpha_s = (float*)(ws + off); off += sizeof(float) * (size_t)LTOT * 4;
    float* alpha_d = (float*)(ws + off); off += sizeof(float) * (size_t)LTOT * 4;
    u16* WT     = (u16*)(ws + off);    off += sizeof(u16) * (size_t)NMETA * 128 * 128;
    u16* W1T    = (u16*)(ws + off);    off += sizeof(u16) * (size_t)128 * 128;
    int* eidx   = (int*)(ws + off);    off += sizeof(int) * (size_t)NMETA * NBUCK * BCAP;
    // union region (disjoint lifetimes): pairs (build1->build2), z (gather->end)
    unsigned long long* pairs = (unsigned long long*)(ws + off);
    u16* z = (u16*)(ws + off);
    off += sizeof(u16) * (size_t)N_NODES * NMETA * 128;                  // 38.4 MB (largest)
    if (ws_size < off) return;  // ~93 MB needed; loud failure if undersized

    hipMemsetAsync(d_ws, 0, zero_bytes, stream);

    // build1: csrA (441 blocks) || prep_w (256 blocks)
    k_build1<<<dim3(NMETA * NCHUNK + 256), 256, 0, stream>>>(ei, gcnt, pairs, W, W1, WT, W1T);
    // build2: csrB (294 blocks) || gemm_h+alpha (2346 blocks)
    k_build2<<<dim3(NMETA * NBUCK + 782 * NMETA), 256, 0, stream>>>(
        gcnt, pairs, row_start, row_end, eidx,
        x, WT, att_src, att_dst, h, alpha_s, alpha_d);
    k_gather<<<dim3((LTOT + 3) / 4), 256, 0, stream>>>(row_start, row_end, eidx,
                                                       alpha_s, alpha_d, h,
                                                       bias, gamma, lbeta, z);
    k_sem<<<dim3((LTOT / 16 + 3) / 4), 256, 0, stream>>>(z, W1T, b1, W2, wpart);
    k_beta<<<1, 64, 0, stream>>>(wpart, betab, (float*)d_out + (size_t)N_NODES * 128);
    k_combine<<<dim3((N_NODES * 64 + 255) / 256), 256, 0, stream>>>(z, betab, (float*)d_out);
}